// Round 1
// baseline (263.504 us; speedup 1.0000x reference)
//
#include <hip/hip_runtime.h>
#include <math.h>

typedef unsigned short u16;
typedef unsigned int u32;
using short8 = __attribute__((ext_vector_type(8))) short;
using f32x4  = __attribute__((ext_vector_type(4))) float;

#define SEQ 2048
#define NH 8
#define DM 512
#define DH 64
#define NROWS 4096  // B*S
#define BATCH 2

__device__ __forceinline__ float bf2f(u16 u) {
  union { u32 i; float f; } c; c.i = ((u32)u) << 16; return c.f;
}
__device__ __forceinline__ u16 f2bf(float f) {
  union { float f; u32 i; } c; c.f = f;
  u32 r = c.i + 0x7fffu + ((c.i >> 16) & 1u);
  return (u16)(r >> 16);
}

// ---------------- LayerNorm (fp32 in -> bf16 out), one wave per 512-row ----
__global__ __launch_bounds__(64) void ln_bf16_kernel(
    const float* __restrict__ x, const float* __restrict__ gw,
    const float* __restrict__ bw, u16* __restrict__ out)
{
  int row = blockIdx.x;
  int lane = threadIdx.x;
  const float* xr = x + (size_t)row * DM;
  float4 v0 = ((const float4*)xr)[lane];
  float4 v1 = ((const float4*)xr)[lane + 64];
  float s  = v0.x + v0.y + v0.z + v0.w + v1.x + v1.y + v1.z + v1.w;
  float s2 = v0.x*v0.x + v0.y*v0.y + v0.z*v0.z + v0.w*v0.w
           + v1.x*v1.x + v1.y*v1.y + v1.z*v1.z + v1.w*v1.w;
  #pragma unroll
  for (int m = 1; m < 64; m <<= 1) {
    s  += __shfl_xor(s,  m);
    s2 += __shfl_xor(s2, m);
  }
  float mu   = s * (1.0f / DM);
  float var  = s2 * (1.0f / DM) - mu * mu;
  float rstd = rsqrtf(var + 1e-5f);
  float4 ga = ((const float4*)gw)[lane],      ba = ((const float4*)bw)[lane];
  float4 gb = ((const float4*)gw)[lane + 64], bb = ((const float4*)bw)[lane + 64];
  ushort4 o0, o1;
  o0.x = f2bf((v0.x - mu) * rstd * ga.x + ba.x);
  o0.y = f2bf((v0.y - mu) * rstd * ga.y + ba.y);
  o0.z = f2bf((v0.z - mu) * rstd * ga.z + ba.z);
  o0.w = f2bf((v0.w - mu) * rstd * ga.w + ba.w);
  o1.x = f2bf((v1.x - mu) * rstd * gb.x + bb.x);
  o1.y = f2bf((v1.y - mu) * rstd * gb.y + bb.y);
  o1.z = f2bf((v1.z - mu) * rstd * gb.z + bb.z);
  o1.w = f2bf((v1.w - mu) * rstd * gb.w + bb.w);
  *(ushort4*)&out[(size_t)row * DM + lane * 4]       = o0;
  *(ushort4*)&out[(size_t)row * DM + 256 + lane * 4] = o1;
}

// ---------------- Transpose + cast fp32 (K x N) -> bf16 (N x K) ------------
__global__ __launch_bounds__(256) void transpose_cast_kernel(
    const float* __restrict__ W, u16* __restrict__ Wt, int K, int N)
{
  __shared__ float tile[32][33];
  int bn = blockIdx.x * 32, bk = blockIdx.y * 32;
  int tx = threadIdx.x & 31, ty = threadIdx.x >> 5; // 32 x 8
  #pragma unroll
  for (int i = 0; i < 32; i += 8)
    tile[ty + i][tx] = W[(size_t)(bk + ty + i) * N + bn + tx];
  __syncthreads();
  #pragma unroll
  for (int i = 0; i < 32; i += 8)
    Wt[(size_t)(bn + ty + i) * K + bk + tx] = f2bf(tile[tx][ty + i]);
}

// ---------------- Elementwise cast fp32 -> bf16 ----------------------------
__global__ __launch_bounds__(256) void cast_bf16_kernel(
    const float* __restrict__ in, u16* __restrict__ out, int n)
{
  int i = (blockIdx.x * 256 + threadIdx.x) * 4;
  if (i >= n) return;
  float4 v = *(const float4*)&in[i];
  ushort4 o;
  o.x = f2bf(v.x); o.y = f2bf(v.y); o.z = f2bf(v.z); o.w = f2bf(v.w);
  *(ushort4*)&out[i] = o;
}

// ---------------- Generic 128x128 MFMA GEMM with fused epilogues -----------
// A: M x K bf16 row-major. Bt: N x K bf16 row-major (= B transposed).
// MODE 0: qkv scatter (q scaled by 0.125) -> outB0/1/2 as [B,H,S,D] bf16
// MODE 1: outF = acc + bias + res (fp32)
// MODE 2: outB0 = gelu(acc + bias) (bf16)
// MODE 3: outF = acc + bias + res (fp32)
template<int MODE>
__global__ __launch_bounds__(256) void gemm_bf16(
    const u16* __restrict__ A, const u16* __restrict__ Bt,
    const float* __restrict__ bias, const float* __restrict__ res,
    float* __restrict__ outF, u16* __restrict__ outB0,
    u16* __restrict__ outB1, u16* __restrict__ outB2,
    int M, int N, int K)
{
  __shared__ u16 sA[128][40];
  __shared__ u16 sB[128][40];
  int tid = threadIdx.x;
  int lane = tid & 63, wv = tid >> 6;
  int wm = wv >> 1, wn = wv & 1;
  int g = lane >> 4, l15 = lane & 15;
  int m0 = blockIdx.y * 128, n0 = blockIdx.x * 128;
  int lr = tid >> 2, lc = (tid & 3) * 8;

  f32x4 acc[4][4] = {};
  for (int k0 = 0; k0 < K; k0 += 32) {
    __syncthreads();
    *(short8*)&sA[lr][lc]      = *(const short8*)&A[(size_t)(m0 + lr) * K + k0 + lc];
    *(short8*)&sA[lr + 64][lc] = *(const short8*)&A[(size_t)(m0 + lr + 64) * K + k0 + lc];
    *(short8*)&sB[lr][lc]      = *(const short8*)&Bt[(size_t)(n0 + lr) * K + k0 + lc];
    *(short8*)&sB[lr + 64][lc] = *(const short8*)&Bt[(size_t)(n0 + lr + 64) * K + k0 + lc];
    __syncthreads();
    short8 af[4], bfr[4];
    #pragma unroll
    for (int i = 0; i < 4; ++i) af[i]  = *(const short8*)&sA[wm * 64 + i * 16 + l15][g * 8];
    #pragma unroll
    for (int i = 0; i < 4; ++i) bfr[i] = *(const short8*)&sB[wn * 64 + i * 16 + l15][g * 8];
    #pragma unroll
    for (int mi = 0; mi < 4; ++mi)
      #pragma unroll
      for (int ni = 0; ni < 4; ++ni)
        acc[mi][ni] = __builtin_amdgcn_mfma_f32_16x16x32_bf16(af[mi], bfr[ni], acc[mi][ni], 0, 0, 0);
  }

  #pragma unroll
  for (int mi = 0; mi < 4; ++mi) {
    #pragma unroll
    for (int ni = 0; ni < 4; ++ni) {
      #pragma unroll
      for (int r = 0; r < 4; ++r) {
        int grow = m0 + wm * 64 + mi * 16 + g * 4 + r;
        int gcol = n0 + wn * 64 + ni * 16 + l15;
        float val = acc[mi][ni][r] + bias[gcol];
        if (MODE == 0) {
          int part = gcol >> 9, c = gcol & 511;
          int hh = c >> 6, dd = c & 63;
          int bb = grow >> 11, ss = grow & 2047;
          size_t dst = (((size_t)(bb * NH + hh)) * SEQ + ss) * DH + dd;
          if (part == 0)      outB0[dst] = f2bf(val * 0.125f);  // q, pre-scaled
          else if (part == 1) outB1[dst] = f2bf(val);           // k
          else                outB2[dst] = f2bf(val);           // v
        } else if (MODE == 1 || MODE == 3) {
          size_t idx = (size_t)grow * DM + gcol;
          outF[idx] = val + res[idx];
        } else { // MODE 2: gelu (tanh approx, matches jax.nn.gelu default)
          float t = val;
          float inner = 0.7978845608028654f * (t + 0.044715f * t * t * t);
          float gl = 0.5f * t * (1.0f + tanhf(inner));
          outB0[(size_t)grow * N + gcol] = f2bf(gl);
        }
      }
    }
  }
}

// ---------------- Flash causal attention with relative positions -----------
// Q/K/V: [B*H, S, 64] bf16 (q pre-scaled by 0.125). E: [H, 2048, 64] bf16.
// Out: [B, S, H*64] bf16. Grid: (S/64, B*H), block 256 (4 waves x 16 q-rows).
__global__ __launch_bounds__(256) void attn_kernel(
    const u16* __restrict__ Q, const u16* __restrict__ Kb,
    const u16* __restrict__ Vb, const u16* __restrict__ Eb,
    u16* __restrict__ Ob)
{
  __shared__ u16 sK[64][72];          // [t][d], padded
  __shared__ u16 sV[64][72];          // transposed: [d][t]
  __shared__ u16 sP[4][16][72];       // per-wave P tiles [srow][tcol]
  __shared__ float sRel[4][16][84];   // per-wave rel strips [srow][c]

  int tid = threadIdx.x, lane = tid & 63, wv = tid >> 6;
  int g = lane >> 4, l15 = lane & 15;
  int bh = blockIdx.y, hh = bh & (NH - 1), bb = bh >> 3;
  int s0 = blockIdx.x * 64;
  int sw = s0 + wv * 16;

  const u16* Qh = Q  + (size_t)bh * SEQ * DH;
  const u16* Kh = Kb + (size_t)bh * SEQ * DH;
  const u16* Vh = Vb + (size_t)bh * SEQ * DH;
  const u16* Eh = Eb + (size_t)hh * SEQ * DH;

  short8 qf[2];
  qf[0] = *(const short8*)&Qh[(size_t)(sw + l15) * DH + g * 8];
  qf[1] = *(const short8*)&Qh[(size_t)(sw + l15) * DH + g * 8 + 32];

  f32x4 o[4] = {};
  float mrow[4] = {-3e38f, -3e38f, -3e38f, -3e38f};
  float lsum[4] = {};

  int rstage = tid >> 3, cstage = (tid & 7) * 8;

  for (int t0 = 0; t0 <= s0; t0 += 64) {
    __syncthreads();
    #pragma unroll
    for (int it = 0; it < 2; ++it) {
      int t = rstage + it * 32;
      *(short8*)&sK[t][cstage] = *(const short8*)&Kh[(size_t)(t0 + t) * DH + cstage];
      short8 vvv = *(const short8*)&Vh[(size_t)(t0 + t) * DH + cstage];
      #pragma unroll
      for (int j = 0; j < 8; ++j) sV[cstage + j][t] = (u16)vvv[j];
    }
    __syncthreads();

    // S1 = Q K^T (16x64 per wave)
    f32x4 accS[4] = {};
    #pragma unroll
    for (int kk = 0; kk < 2; ++kk)
      #pragma unroll
      for (int ni = 0; ni < 4; ++ni) {
        short8 kf = *(const short8*)&sK[ni * 16 + l15][kk * 32 + g * 8];
        accS[ni] = __builtin_amdgcn_mfma_f32_16x16x32_bf16(qf[kk], kf, accS[ni], 0, 0, 0);
      }

    // S2 = Q E^T strip (16x80 per wave): rel[s,t] = q[s].E[2047-s+t]
    int jbase = 2032 - sw + t0;  // >= 0 always
    f32x4 accR[5] = {};
    #pragma unroll
    for (int kk = 0; kk < 2; ++kk)
      #pragma unroll
      for (int nb = 0; nb < 5; ++nb) {
        int j = jbase + nb * 16 + l15;
        if (j > 2047) j = 2047;  // only masked entries hit the clamp
        short8 ef = *(const short8*)&Eh[(size_t)j * DH + kk * 32 + g * 8];
        accR[nb] = __builtin_amdgcn_mfma_f32_16x16x32_bf16(qf[kk], ef, accR[nb], 0, 0, 0);
      }
    #pragma unroll
    for (int nb = 0; nb < 5; ++nb)
      #pragma unroll
      for (int r = 0; r < 4; ++r)
        sRel[wv][g * 4 + r][nb * 16 + l15] = accR[nb][r];
    asm volatile("s_waitcnt lgkmcnt(0)" ::: "memory");

    // combine + causal mask + online softmax
    float pv[4][4];
    float tmax[4] = {-3e38f, -3e38f, -3e38f, -3e38f};
    #pragma unroll
    for (int ni = 0; ni < 4; ++ni)
      #pragma unroll
      for (int r = 0; r < 4; ++r) {
        int srow = g * 4 + r, tcol = ni * 16 + l15;
        float val = accS[ni][r] + sRel[wv][srow][15 - srow + tcol];
        if (t0 + tcol > sw + srow) val = -3e38f;
        pv[ni][r] = val;
        tmax[r] = fmaxf(tmax[r], val);
      }
    #pragma unroll
    for (int r = 0; r < 4; ++r) {
      tmax[r] = fmaxf(tmax[r], __shfl_xor(tmax[r], 1));
      tmax[r] = fmaxf(tmax[r], __shfl_xor(tmax[r], 2));
      tmax[r] = fmaxf(tmax[r], __shfl_xor(tmax[r], 4));
      tmax[r] = fmaxf(tmax[r], __shfl_xor(tmax[r], 8));
    }
    float scl[4];
    #pragma unroll
    for (int r = 0; r < 4; ++r) {
      float mnew = fmaxf(mrow[r], tmax[r]);
      scl[r] = __expf(mrow[r] - mnew);
      mrow[r] = mnew;
      float se = 0.f;
      #pragma unroll
      for (int ni = 0; ni < 4; ++ni) {
        float p = __expf(pv[ni][r] - mnew);
        pv[ni][r] = p;
        se += p;
      }
      se += __shfl_xor(se, 1); se += __shfl_xor(se, 2);
      se += __shfl_xor(se, 4); se += __shfl_xor(se, 8);
      lsum[r] = lsum[r] * scl[r] + se;
    }
    #pragma unroll
    for (int nb = 0; nb < 4; ++nb)
      #pragma unroll
      for (int r = 0; r < 4; ++r) o[nb][r] *= scl[r];

    // P -> LDS (D-layout to A-layout realignment), then PV
    #pragma unroll
    for (int ni = 0; ni < 4; ++ni)
      #pragma unroll
      for (int r = 0; r < 4; ++r)
        sP[wv][g * 4 + r][ni * 16 + l15] = f2bf(pv[ni][r]);
    asm volatile("s_waitcnt lgkmcnt(0)" ::: "memory");
    #pragma unroll
    for (int kk = 0; kk < 2; ++kk) {
      short8 pf = *(const short8*)&sP[wv][l15][kk * 32 + g * 8];
      #pragma unroll
      for (int nb = 0; nb < 4; ++nb) {
        short8 vf = *(const short8*)&sV[nb * 16 + l15][kk * 32 + g * 8];
        o[nb] = __builtin_amdgcn_mfma_f32_16x16x32_bf16(pf, vf, o[nb], 0, 0, 0);
      }
    }
  }

  #pragma unroll
  for (int nb = 0; nb < 4; ++nb)
    #pragma unroll
    for (int r = 0; r < 4; ++r) {
      int ss = sw + g * 4 + r, dd = nb * 16 + l15;
      Ob[((size_t)(bb * SEQ + ss)) * DM + hh * DH + dd] = f2bf(o[nb][r] / lsum[r]);
    }
}

// ---------------------------------------------------------------------------
extern "C" void kernel_launch(void* const* d_in, const int* in_sizes, int n_in,
                              void* d_out, int out_size, void* d_ws, size_t ws_size,
                              hipStream_t stream) {
  const float* x     = (const float*)d_in[0];
  // d_in[1] = mask: recomputed causally in-kernel
  const float* Wqkv  = (const float*)d_in[2];
  const float* bqkv  = (const float*)d_in[3];
  const float* Wproj = (const float*)d_in[4];
  const float* bproj = (const float*)d_in[5];
  const float* E     = (const float*)d_in[6];
  const float* g1    = (const float*)d_in[7];
  const float* b1    = (const float*)d_in[8];
  const float* g2    = (const float*)d_in[9];
  const float* b2    = (const float*)d_in[10];
  const float* W1    = (const float*)d_in[11];
  const float* bm1   = (const float*)d_in[12];
  const float* W2    = (const float*)d_in[13];
  const float* bm2   = (const float*)d_in[14];
  float* out = (float*)d_out;

  char* ws = (char*)d_ws;
  size_t off = 0;
  auto alloc = [&](size_t bytes) {
    void* p = ws + off;
    off += (bytes + 255) & ~(size_t)255;
    return p;
  };
  u16* a_bf   = (u16*)alloc((size_t)NROWS * DM * 2);      // LN1 out, reused for LN2 out
  u16* q_bf   = (u16*)alloc((size_t)NROWS * DM * 2);
  u16* k_bf   = (u16*)alloc((size_t)NROWS * DM * 2);
  u16* v_bf   = (u16*)alloc((size_t)NROWS * DM * 2);
  u16* att_bf = (u16*)alloc((size_t)NROWS * DM * 2);
  float* y    = (float*)alloc((size_t)NROWS * DM * 4);
  u16* h_bf   = (u16*)alloc((size_t)NROWS * 2048 * 2);
  u16* WqkvT  = (u16*)alloc((size_t)1536 * 512 * 2);
  u16* WprojT = (u16*)alloc((size_t)512 * 512 * 2);
  u16* W1T    = (u16*)alloc((size_t)2048 * 512 * 2);
  u16* W2T    = (u16*)alloc((size_t)512 * 2048 * 2);
  u16* E_bf   = (u16*)alloc((size_t)NH * SEQ * DH * 2);

  // weights -> bf16 (transposed to N x K)
  transpose_cast_kernel<<<dim3(1536 / 32, 512 / 32), 256, 0, stream>>>(Wqkv, WqkvT, 512, 1536);
  transpose_cast_kernel<<<dim3(512 / 32, 512 / 32), 256, 0, stream>>>(Wproj, WprojT, 512, 512);
  transpose_cast_kernel<<<dim3(2048 / 32, 512 / 32), 256, 0, stream>>>(W1, W1T, 512, 2048);
  transpose_cast_kernel<<<dim3(512 / 32, 2048 / 32), 256, 0, stream>>>(W2, W2T, 2048, 512);
  cast_bf16_kernel<<<(NH * SEQ * DH) / (256 * 4), 256, 0, stream>>>(E, E_bf, NH * SEQ * DH);

  // LN1
  ln_bf16_kernel<<<NROWS, 64, 0, stream>>>(x, g1, b1, a_bf);
  // QKV
  gemm_bf16<0><<<dim3(1536 / 128, NROWS / 128), 256, 0, stream>>>(
      a_bf, WqkvT, bqkv, nullptr, nullptr, q_bf, k_bf, v_bf, NROWS, 1536, 512);
  // attention
  attn_kernel<<<dim3(SEQ / 64, BATCH * NH), 256, 0, stream>>>(q_bf, k_bf, v_bf, E_bf, att_bf);
  // proj + residual -> y (fp32)
  gemm_bf16<1><<<dim3(512 / 128, NROWS / 128), 256, 0, stream>>>(
      att_bf, WprojT, bproj, x, y, nullptr, nullptr, nullptr, NROWS, 512, 512);
  // LN2 (reuse a_bf as m_bf)
  ln_bf16_kernel<<<NROWS, 64, 0, stream>>>(y, g2, b2, a_bf);
  // FFN1 + gelu
  gemm_bf16<2><<<dim3(2048 / 128, NROWS / 128), 256, 0, stream>>>(
      a_bf, W1T, bm1, nullptr, nullptr, h_bf, nullptr, nullptr, NROWS, 2048, 512);
  // FFN2 + residual -> out
  gemm_bf16<3><<<dim3(512 / 128, NROWS / 128), 256, 0, stream>>>(
      h_bf, W2T, bm2, y, out, nullptr, nullptr, nullptr, NROWS, 512, 2048);
}

// Round 2
// 228.024 us; speedup vs baseline: 1.1556x; 1.1556x over previous
//
#include <hip/hip_runtime.h>
#include <math.h>

typedef unsigned short u16;
typedef unsigned int u32;
using short8 = __attribute__((ext_vector_type(8))) short;
using f32x4  = __attribute__((ext_vector_type(4))) float;

#define SEQ 2048
#define NH 8
#define DM 512
#define DH 64
#define NROWS 4096  // B*S
#define BATCH 2

__device__ __forceinline__ float bf2f(u16 u) {
  union { u32 i; float f; } c; c.i = ((u32)u) << 16; return c.f;
}
__device__ __forceinline__ u16 f2bf(float f) {
  union { float f; u32 i; } c; c.f = f;
  u32 r = c.i + 0x7fffu + ((c.i >> 16) & 1u);
  return (u16)(r >> 16);
}

// async global->LDS, 16B per lane. LDS dest must be wave-uniform base.
__device__ __forceinline__ void gll16(const u16* g, u16* l) {
  __builtin_amdgcn_global_load_lds(
      (const __attribute__((address_space(1))) u32*)g,
      (__attribute__((address_space(3))) u32*)l, 16, 0, 0);
}

// ---------------- LayerNorm (fp32 in -> bf16 out), one wave per 512-row ----
__global__ __launch_bounds__(64) void ln_bf16_kernel(
    const float* __restrict__ x, const float* __restrict__ gw,
    const float* __restrict__ bw, u16* __restrict__ out)
{
  int row = blockIdx.x;
  int lane = threadIdx.x;
  const float* xr = x + (size_t)row * DM;
  float4 v0 = ((const float4*)xr)[lane];
  float4 v1 = ((const float4*)xr)[lane + 64];
  float s  = v0.x + v0.y + v0.z + v0.w + v1.x + v1.y + v1.z + v1.w;
  float s2 = v0.x*v0.x + v0.y*v0.y + v0.z*v0.z + v0.w*v0.w
           + v1.x*v1.x + v1.y*v1.y + v1.z*v1.z + v1.w*v1.w;
  #pragma unroll
  for (int m = 1; m < 64; m <<= 1) {
    s  += __shfl_xor(s,  m);
    s2 += __shfl_xor(s2, m);
  }
  float mu   = s * (1.0f / DM);
  float var  = s2 * (1.0f / DM) - mu * mu;
  float rstd = rsqrtf(var + 1e-5f);
  float4 ga = ((const float4*)gw)[lane],      ba = ((const float4*)bw)[lane];
  float4 gb = ((const float4*)gw)[lane + 64], bb = ((const float4*)bw)[lane + 64];
  ushort4 o0, o1;
  o0.x = f2bf((v0.x - mu) * rstd * ga.x + ba.x);
  o0.y = f2bf((v0.y - mu) * rstd * ga.y + ba.y);
  o0.z = f2bf((v0.z - mu) * rstd * ga.z + ba.z);
  o0.w = f2bf((v0.w - mu) * rstd * ga.w + ba.w);
  o1.x = f2bf((v1.x - mu) * rstd * gb.x + bb.x);
  o1.y = f2bf((v1.y - mu) * rstd * gb.y + bb.y);
  o1.z = f2bf((v1.z - mu) * rstd * gb.z + bb.z);
  o1.w = f2bf((v1.w - mu) * rstd * gb.w + bb.w);
  *(ushort4*)&out[(size_t)row * DM + lane * 4]       = o0;
  *(ushort4*)&out[(size_t)row * DM + 256 + lane * 4] = o1;
}

// ---------------- Transpose + cast fp32 (K x N) -> bf16 (N x K) ------------
__global__ __launch_bounds__(256) void transpose_cast_kernel(
    const float* __restrict__ W, u16* __restrict__ Wt, int K, int N)
{
  __shared__ float tile[32][33];
  int bn = blockIdx.x * 32, bk = blockIdx.y * 32;
  int tx = threadIdx.x & 31, ty = threadIdx.x >> 5; // 32 x 8
  #pragma unroll
  for (int i = 0; i < 32; i += 8)
    tile[ty + i][tx] = W[(size_t)(bk + ty + i) * N + bn + tx];
  __syncthreads();
  #pragma unroll
  for (int i = 0; i < 32; i += 8)
    Wt[(size_t)(bn + ty + i) * K + bk + tx] = f2bf(tile[tx][ty + i]);
}

// ---------------- Elementwise cast fp32 -> bf16 ----------------------------
__global__ __launch_bounds__(256) void cast_bf16_kernel(
    const float* __restrict__ in, u16* __restrict__ out, int n)
{
  int i = (blockIdx.x * 256 + threadIdx.x) * 4;
  if (i >= n) return;
  float4 v = *(const float4*)&in[i];
  ushort4 o;
  o.x = f2bf(v.x); o.y = f2bf(v.y); o.z = f2bf(v.z); o.w = f2bf(v.w);
  *(ushort4*)&out[i] = o;
}

// ---------------- 128xTN MFMA GEMM, BK=64, global_load_lds staging ---------
// A: M x K bf16 row-major. Bt: N x K bf16 row-major. LDS chunk-XOR swizzled.
// MODE 0: qkv scatter (q scaled by 0.125*log2e) -> outB0/1/2 as [B,H,S,D]
// MODE 1/3: outF = acc + bias + res (fp32)
// MODE 2: outB0 = gelu(acc + bias) (bf16)
template<int TN, int MODE>
__global__ __launch_bounds__(256) void gemm_bf16(
    const u16* __restrict__ A, const u16* __restrict__ Bt,
    const float* __restrict__ bias, const float* __restrict__ res,
    float* __restrict__ outF, u16* __restrict__ outB0,
    u16* __restrict__ outB1, u16* __restrict__ outB2,
    int M, int N, int K)
{
  constexpr int NI = TN / 32;       // n-frags per wave
  __shared__ u16 sA[128 * 64];
  __shared__ u16 sB[TN * 64];
  int tid = threadIdx.x;
  int lane = tid & 63, wv = tid >> 6;
  int wm = wv >> 1, wn = wv & 1;
  int g = lane >> 4, l15 = lane & 15;
  int m0 = blockIdx.y * 128, n0 = blockIdx.x * TN;

  f32x4 acc[4][NI] = {};
  for (int k0 = 0; k0 < K; k0 += 64) {
    __syncthreads();
    #pragma unroll
    for (int s = 0; s < 4; ++s) {           // A: 128 rows x 8 chunks
      int c = s * 256 + tid;
      int row = c >> 3, p = c & 7;
      gll16(&A[(size_t)(m0 + row) * K + k0 + ((p ^ (row & 7)) * 8)],
            &sA[(size_t)(s * 256 + wv * 64) * 8]);
    }
    #pragma unroll
    for (int s = 0; s < TN / 32; ++s) {     // B: TN rows x 8 chunks
      int c = s * 256 + tid;
      int row = c >> 3, p = c & 7;
      gll16(&Bt[(size_t)(n0 + row) * K + k0 + ((p ^ (row & 7)) * 8)],
            &sB[(size_t)(s * 256 + wv * 64) * 8]);
    }
    asm volatile("s_waitcnt vmcnt(0)" ::: "memory");
    __syncthreads();
    #pragma unroll
    for (int kk = 0; kk < 2; ++kk) {
      short8 af[4], bfr[NI];
      #pragma unroll
      for (int i = 0; i < 4; ++i) {
        int row = wm * 64 + i * 16 + l15;
        af[i] = *(const short8*)&sA[row * 64 + (((4 * kk + g) ^ (row & 7)) * 8)];
      }
      #pragma unroll
      for (int i = 0; i < NI; ++i) {
        int row = wn * (TN / 2) + i * 16 + l15;
        bfr[i] = *(const short8*)&sB[row * 64 + (((4 * kk + g) ^ (row & 7)) * 8)];
      }
      #pragma unroll
      for (int mi = 0; mi < 4; ++mi)
        #pragma unroll
        for (int ni = 0; ni < NI; ++ni)
          acc[mi][ni] = __builtin_amdgcn_mfma_f32_16x16x32_bf16(af[mi], bfr[ni], acc[mi][ni], 0, 0, 0);
    }
  }

  #pragma unroll
  for (int mi = 0; mi < 4; ++mi) {
    #pragma unroll
    for (int ni = 0; ni < NI; ++ni) {
      #pragma unroll
      for (int r = 0; r < 4; ++r) {
        int grow = m0 + wm * 64 + mi * 16 + g * 4 + r;
        int gcol = n0 + wn * (TN / 2) + ni * 16 + l15;
        float val = acc[mi][ni][r] + bias[gcol];
        if (MODE == 0) {
          int part = gcol >> 9, c = gcol & 511;
          int hh = c >> 6, dd = c & 63;
          int bb = grow >> 11, ss = grow & 2047;
          size_t dst = (((size_t)(bb * NH + hh)) * SEQ + ss) * DH + dd;
          if (part == 0)      outB0[dst] = f2bf(val * 0.18033688011112042f); // q * 0.125*log2(e)
          else if (part == 1) outB1[dst] = f2bf(val);           // k
          else                outB2[dst] = f2bf(val);           // v
        } else if (MODE == 1 || MODE == 3) {
          size_t idx = (size_t)grow * DM + gcol;
          outF[idx] = val + res[idx];
        } else { // MODE 2: gelu (tanh approx = jax.nn.gelu default)
          float t = val;
          float inner = 0.7978845608028654f * (t + 0.044715f * t * t * t);
          float gl = 0.5f * t * (1.0f + tanhf(inner));
          outB0[(size_t)grow * N + gcol] = f2bf(gl);
        }
      }
    }
  }
}

// ---------------- Flash causal attention with relative positions -----------
// Q/K/V: [B*H, S, 64] bf16 (q pre-scaled by 0.125*log2e). E: [H, 2048, 64].
// Out: [B, S, H*64] bf16. Grid: (S/64, B*H), block 256 (4 waves x 16 q-rows).
// K double-buffered via global_load_lds (source chunk-XOR swizzle);
// V double-buffered transposed via reg staging ((t>>3)^(d>>3) block XOR);
// rel skew realign done with __shfl (no LDS round-trip).
__global__ __launch_bounds__(256) void attn_kernel(
    const u16* __restrict__ Q, const u16* __restrict__ Kb,
    const u16* __restrict__ Vb, const u16* __restrict__ Eb,
    u16* __restrict__ Ob)
{
  __shared__ u16 sK[2][64 * 64];   // linear chunks, source-swizzled (16KB)
  __shared__ u16 sV[2][64 * 72];   // [d][72], block-XOR          (18KB)
  __shared__ u16 sP[4][16 * 64];   // per-wave, block-XOR          (8KB)

  int tid = threadIdx.x, lane = tid & 63, wv = tid >> 6;
  int g = lane >> 4, l15 = lane & 15;
  int bh = blockIdx.y, hh = bh & (NH - 1), bb = bh >> 3;
  int s0 = blockIdx.x * 64;
  int sw = s0 + wv * 16;

  const u16* Qh = Q  + (size_t)bh * SEQ * DH;
  const u16* Kh = Kb + (size_t)bh * SEQ * DH;
  const u16* Vh = Vb + (size_t)bh * SEQ * DH;
  const u16* Eh = Eb + (size_t)hh * SEQ * DH;

  short8 qf[2];
  qf[0] = *(const short8*)&Qh[(size_t)(sw + l15) * DH + g * 8];
  qf[1] = *(const short8*)&Qh[(size_t)(sw + l15) * DH + g * 8 + 32];

  f32x4 o[4] = {};
  float mrow[4] = {-1e30f, -1e30f, -1e30f, -1e30f};
  float lsum[4] = {};

  int rstage = tid >> 3, cstage = (tid & 7) * 8;
  int niter = s0 / 64 + 1;

  // ---- prologue: stage tile 0 ----
  #pragma unroll
  for (int s = 0; s < 2; ++s) {
    int c = s * 256 + tid, t = c >> 3, p = c & 7;
    gll16(&Kh[(size_t)t * DH + ((p ^ (t & 7)) * 8)],
          &sK[0][(size_t)(s * 256 + wv * 64) * 8]);
  }
  {
    short8 v0 = *(const short8*)&Vh[(size_t)rstage * DH + cstage];
    short8 v1 = *(const short8*)&Vh[(size_t)(rstage + 32) * DH + cstage];
    #pragma unroll
    for (int j = 0; j < 8; ++j) {
      int d0 = cstage + j;
      sV[0][d0 * 72 + (((rstage >> 3) ^ (d0 >> 3)) * 8) + (rstage & 7)] = (u16)v0[j];
      int t1 = rstage + 32;
      sV[0][d0 * 72 + (((t1 >> 3) ^ (d0 >> 3)) * 8) + (t1 & 7)] = (u16)v1[j];
    }
  }
  asm volatile("s_waitcnt vmcnt(0)" ::: "memory");
  __syncthreads();

  for (int i = 0; i < niter; ++i) {
    int t0 = i * 64, cur = i & 1;
    bool pre = (i + 1 < niter);
    short8 vp0, vp1;
    if (pre) {
      // prefetch next K tile (async -> LDS) and V tile (-> regs)
      #pragma unroll
      for (int s = 0; s < 2; ++s) {
        int c = s * 256 + tid, t = c >> 3, p = c & 7;
        gll16(&Kh[(size_t)(t0 + 64 + t) * DH + ((p ^ (t & 7)) * 8)],
              &sK[cur ^ 1][(size_t)(s * 256 + wv * 64) * 8]);
      }
      vp0 = *(const short8*)&Vh[(size_t)(t0 + 64 + rstage) * DH + cstage];
      vp1 = *(const short8*)&Vh[(size_t)(t0 + 96 + rstage) * DH + cstage];
    }

    // E loads (hoisted ahead of QK MFMAs to hide latency)
    int jbase = 2032 - sw + t0;
    short8 ef0[5], ef1[5];
    #pragma unroll
    for (int nb = 0; nb < 5; ++nb) {
      int j = jbase + nb * 16 + l15; if (j > 2047) j = 2047;
      ef0[nb] = *(const short8*)&Eh[(size_t)j * DH + g * 8];
    }

    // S1 = Q K^T (16x64 per wave) from swizzled sK
    f32x4 accS[4] = {};
    #pragma unroll
    for (int kk = 0; kk < 2; ++kk)
      #pragma unroll
      for (int ni = 0; ni < 4; ++ni) {
        int row = ni * 16 + l15;
        short8 kf = *(const short8*)&sK[cur][row * 64 + (((4 * kk + g) ^ (row & 7)) * 8)];
        accS[ni] = __builtin_amdgcn_mfma_f32_16x16x32_bf16(qf[kk], kf, accS[ni], 0, 0, 0);
      }

    #pragma unroll
    for (int nb = 0; nb < 5; ++nb) {
      int j = jbase + nb * 16 + l15; if (j > 2047) j = 2047;
      ef1[nb] = *(const short8*)&Eh[(size_t)j * DH + 32 + g * 8];
    }

    // S2 = Q E^T strip (16x80 per wave): rel[s,t] = q[s].E[jbase + 15-s+t]
    f32x4 accR[5] = {};
    #pragma unroll
    for (int nb = 0; nb < 5; ++nb)
      accR[nb] = __builtin_amdgcn_mfma_f32_16x16x32_bf16(qf[0], ef0[nb], accR[nb], 0, 0, 0);
    #pragma unroll
    for (int nb = 0; nb < 5; ++nb)
      accR[nb] = __builtin_amdgcn_mfma_f32_16x16x32_bf16(qf[1], ef1[nb], accR[nb], 0, 0, 0);

    // skew realign via in-group shuffles + combine + mask + online softmax
    float pv[4][4];
    #pragma unroll
    for (int r = 0; r < 4; ++r) {
      int srow = g * 4 + r;
      int dsh = 15 - srow + l15;                    // 0..30
      int srcl = (lane & 48) + (dsh & 15);
      float sh0 = __shfl(accR[0][r], srcl);
      float sh1 = __shfl(accR[1][r], srcl);
      float sh2 = __shfl(accR[2][r], srcl);
      float sh3 = __shfl(accR[3][r], srcl);
      float sh4 = __shfl(accR[4][r], srcl);
      bool cy = dsh >= 16;
      float rel[4] = {cy ? sh1 : sh0, cy ? sh2 : sh1, cy ? sh3 : sh2, cy ? sh4 : sh3};
      #pragma unroll
      for (int ni = 0; ni < 4; ++ni) {
        float val = accS[ni][r] + rel[ni];
        if (t0 + ni * 16 + l15 > sw + srow) val = -1e30f;
        pv[ni][r] = val;
      }
    }
    #pragma unroll
    for (int r = 0; r < 4; ++r) {
      float tm = fmaxf(fmaxf(pv[0][r], pv[1][r]), fmaxf(pv[2][r], pv[3][r]));
      tm = fmaxf(tm, __shfl_xor(tm, 1));
      tm = fmaxf(tm, __shfl_xor(tm, 2));
      tm = fmaxf(tm, __shfl_xor(tm, 4));
      tm = fmaxf(tm, __shfl_xor(tm, 8));
      float mnew = fmaxf(mrow[r], tm);
      float scl = exp2f(mrow[r] - mnew);
      mrow[r] = mnew;
      float se = 0.f;
      #pragma unroll
      for (int ni = 0; ni < 4; ++ni) {
        float p = exp2f(pv[ni][r] - mnew);
        pv[ni][r] = p;
        se += p;
      }
      se += __shfl_xor(se, 1); se += __shfl_xor(se, 2);
      se += __shfl_xor(se, 4); se += __shfl_xor(se, 8);
      lsum[r] = lsum[r] * scl + se;
      #pragma unroll
      for (int nb = 0; nb < 4; ++nb) o[nb][r] *= scl;
    }

    // P -> per-wave LDS (block-XOR layout), then PV from sV[cur]
    #pragma unroll
    for (int ni = 0; ni < 4; ++ni)
      #pragma unroll
      for (int r = 0; r < 4; ++r) {
        int srow = g * 4 + r;
        sP[wv][srow * 64 + (((2 * ni + (l15 >> 3)) ^ (srow & 7)) * 8) + (l15 & 7)] = f2bf(pv[ni][r]);
      }
    asm volatile("s_waitcnt lgkmcnt(0)" ::: "memory");
    __builtin_amdgcn_sched_barrier(0);
    #pragma unroll
    for (int kk = 0; kk < 2; ++kk) {
      short8 pf = *(const short8*)&sP[wv][l15 * 64 + (((4 * kk + g) ^ (l15 & 7)) * 8)];
      #pragma unroll
      for (int nb = 0; nb < 4; ++nb) {
        int d = nb * 16 + l15;
        short8 vf = *(const short8*)&sV[cur][d * 72 + (((4 * kk + g) ^ (2 * nb + (l15 >> 3))) * 8)];
        o[nb] = __builtin_amdgcn_mfma_f32_16x16x32_bf16(pf, vf, o[nb], 0, 0, 0);
      }
    }

    // write prefetched V^T into the other buffer; drain K gll; barrier
    if (pre) {
      #pragma unroll
      for (int j = 0; j < 8; ++j) {
        int d0 = cstage + j;
        sV[cur ^ 1][d0 * 72 + (((rstage >> 3) ^ (d0 >> 3)) * 8) + (rstage & 7)] = (u16)vp0[j];
        int t1 = rstage + 32;
        sV[cur ^ 1][d0 * 72 + (((t1 >> 3) ^ (d0 >> 3)) * 8) + (t1 & 7)] = (u16)vp1[j];
      }
    }
    asm volatile("s_waitcnt vmcnt(0)" ::: "memory");
    __syncthreads();
  }

  #pragma unroll
  for (int nb = 0; nb < 4; ++nb)
    #pragma unroll
    for (int r = 0; r < 4; ++r) {
      int ss = sw + g * 4 + r, dd = nb * 16 + l15;
      Ob[((size_t)(bb * SEQ + ss)) * DM + hh * DH + dd] = f2bf(o[nb][r] / lsum[r]);
    }
}

// ---------------------------------------------------------------------------
extern "C" void kernel_launch(void* const* d_in, const int* in_sizes, int n_in,
                              void* d_out, int out_size, void* d_ws, size_t ws_size,
                              hipStream_t stream) {
  const float* x     = (const float*)d_in[0];
  // d_in[1] = mask: recomputed causally in-kernel
  const float* Wqkv  = (const float*)d_in[2];
  const float* bqkv  = (const float*)d_in[3];
  const float* Wproj = (const float*)d_in[4];
  const float* bproj = (const float*)d_in[5];
  const float* E     = (const float*)d_in[6];
  const float* g1    = (const float*)d_in[7];
  const float* b1    = (const float*)d_in[8];
  const float* g2    = (const float*)d_in[9];
  const float* b2    = (const float*)d_in[10];
  const float* W1    = (const float*)d_in[11];
  const float* bm1   = (const float*)d_in[12];
  const float* W2    = (const float*)d_in[13];
  const float* bm2   = (const float*)d_in[14];
  float* out = (float*)d_out;

  char* ws = (char*)d_ws;
  size_t off = 0;
  auto alloc = [&](size_t bytes) {
    void* p = ws + off;
    off += (bytes + 255) & ~(size_t)255;
    return p;
  };
  u16* a_bf   = (u16*)alloc((size_t)NROWS * DM * 2);      // LN1 out, reused for LN2 out
  u16* q_bf   = (u16*)alloc((size_t)NROWS * DM * 2);
  u16* k_bf   = (u16*)alloc((size_t)NROWS * DM * 2);
  u16* v_bf   = (u16*)alloc((size_t)NROWS * DM * 2);
  u16* att_bf = (u16*)alloc((size_t)NROWS * DM * 2);
  float* y    = (float*)alloc((size_t)NROWS * DM * 4);
  u16* h_bf   = (u16*)alloc((size_t)NROWS * 2048 * 2);
  u16* WqkvT  = (u16*)alloc((size_t)1536 * 512 * 2);
  u16* WprojT = (u16*)alloc((size_t)512 * 512 * 2);
  u16* W1T    = (u16*)alloc((size_t)2048 * 512 * 2);
  u16* W2T    = (u16*)alloc((size_t)512 * 2048 * 2);
  u16* E_bf   = (u16*)alloc((size_t)NH * SEQ * DH * 2);

  // weights -> bf16 (transposed to N x K)
  transpose_cast_kernel<<<dim3(1536 / 32, 512 / 32), 256, 0, stream>>>(Wqkv, WqkvT, 512, 1536);
  transpose_cast_kernel<<<dim3(512 / 32, 512 / 32), 256, 0, stream>>>(Wproj, WprojT, 512, 512);
  transpose_cast_kernel<<<dim3(2048 / 32, 512 / 32), 256, 0, stream>>>(W1, W1T, 512, 2048);
  transpose_cast_kernel<<<dim3(512 / 32, 2048 / 32), 256, 0, stream>>>(W2, W2T, 2048, 512);
  cast_bf16_kernel<<<(NH * SEQ * DH) / (256 * 4), 256, 0, stream>>>(E, E_bf, NH * SEQ * DH);

  // LN1
  ln_bf16_kernel<<<NROWS, 64, 0, stream>>>(x, g1, b1, a_bf);
  // QKV (q pre-scaled by 0.125*log2e for exp2-softmax)
  gemm_bf16<128, 0><<<dim3(1536 / 128, NROWS / 128), 256, 0, stream>>>(
      a_bf, WqkvT, bqkv, nullptr, nullptr, q_bf, k_bf, v_bf, NROWS, 1536, 512);
  // attention
  attn_kernel<<<dim3(SEQ / 64, BATCH * NH), 256, 0, stream>>>(q_bf, k_bf, v_bf, E_bf, att_bf);
  // proj + residual -> y (fp32)
  gemm_bf16<64, 1><<<dim3(512 / 64, NROWS / 128), 256, 0, stream>>>(
      att_bf, WprojT, bproj, x, y, nullptr, nullptr, nullptr, NROWS, 512, 512);
  // LN2 (reuse a_bf as m_bf)
  ln_bf16_kernel<<<NROWS, 64, 0, stream>>>(y, g2, b2, a_bf);
  // FFN1 + gelu
  gemm_bf16<128, 2><<<dim3(2048 / 128, NROWS / 128), 256, 0, stream>>>(
      a_bf, W1T, bm1, nullptr, nullptr, h_bf, nullptr, nullptr, NROWS, 2048, 512);
  // FFN2 + residual -> out
  gemm_bf16<64, 3><<<dim3(512 / 64, NROWS / 128), 256, 0, stream>>>(
      h_bf, W2T, bm2, y, out, nullptr, nullptr, nullptr, NROWS, 512, 2048);
}

// Round 3
// 208.804 us; speedup vs baseline: 1.2620x; 1.0921x over previous
//
#include <hip/hip_runtime.h>
#include <math.h>

typedef unsigned short u16;
typedef unsigned int u32;
using short8 = __attribute__((ext_vector_type(8))) short;
using f32x4  = __attribute__((ext_vector_type(4))) float;

#define SEQ 2048
#define NH 8
#define DM 512
#define DH 64
#define NROWS 4096  // B*S
#define BATCH 2
#define KVB 128

__device__ __forceinline__ float bf2f(u16 u) {
  union { u32 i; float f; } c; c.i = ((u32)u) << 16; return c.f;
}
__device__ __forceinline__ u16 f2bf(float f) {
  union { float f; u32 i; } c; c.f = f;
  u32 r = c.i + 0x7fffu + ((c.i >> 16) & 1u);
  return (u16)(r >> 16);
}

// async global->LDS, 16B per lane. LDS dest must be wave-uniform base.
__device__ __forceinline__ void gll16(const u16* g, u16* l) {
  __builtin_amdgcn_global_load_lds(
      (const __attribute__((address_space(1))) u32*)g,
      (__attribute__((address_space(3))) u32*)l, 16, 0, 0);
}

// ---------------- LayerNorm (fp32 in -> bf16 out), one wave per 512-row ----
__global__ __launch_bounds__(64) void ln_bf16_kernel(
    const float* __restrict__ x, const float* __restrict__ gw,
    const float* __restrict__ bw, u16* __restrict__ out)
{
  int row = blockIdx.x;
  int lane = threadIdx.x;
  const float* xr = x + (size_t)row * DM;
  float4 v0 = ((const float4*)xr)[lane];
  float4 v1 = ((const float4*)xr)[lane + 64];
  float s  = v0.x + v0.y + v0.z + v0.w + v1.x + v1.y + v1.z + v1.w;
  float s2 = v0.x*v0.x + v0.y*v0.y + v0.z*v0.z + v0.w*v0.w
           + v1.x*v1.x + v1.y*v1.y + v1.z*v1.z + v1.w*v1.w;
  #pragma unroll
  for (int m = 1; m < 64; m <<= 1) {
    s  += __shfl_xor(s,  m);
    s2 += __shfl_xor(s2, m);
  }
  float mu   = s * (1.0f / DM);
  float var  = s2 * (1.0f / DM) - mu * mu;
  float rstd = rsqrtf(var + 1e-5f);
  float4 ga = ((const float4*)gw)[lane],      ba = ((const float4*)bw)[lane];
  float4 gb = ((const float4*)gw)[lane + 64], bb = ((const float4*)bw)[lane + 64];
  ushort4 o0, o1;
  o0.x = f2bf((v0.x - mu) * rstd * ga.x + ba.x);
  o0.y = f2bf((v0.y - mu) * rstd * ga.y + ba.y);
  o0.z = f2bf((v0.z - mu) * rstd * ga.z + ba.z);
  o0.w = f2bf((v0.w - mu) * rstd * ga.w + ba.w);
  o1.x = f2bf((v1.x - mu) * rstd * gb.x + bb.x);
  o1.y = f2bf((v1.y - mu) * rstd * gb.y + bb.y);
  o1.z = f2bf((v1.z - mu) * rstd * gb.z + bb.z);
  o1.w = f2bf((v1.w - mu) * rstd * gb.w + bb.w);
  *(ushort4*)&out[(size_t)row * DM + lane * 4]       = o0;
  *(ushort4*)&out[(size_t)row * DM + 256 + lane * 4] = o1;
}

// ---------------- Transpose + cast fp32 (K x N) -> bf16 (N x K) ------------
__global__ __launch_bounds__(256) void transpose_cast_kernel(
    const float* __restrict__ W, u16* __restrict__ Wt, int K, int N)
{
  __shared__ float tile[32][33];
  int bn = blockIdx.x * 32, bk = blockIdx.y * 32;
  int tx = threadIdx.x & 31, ty = threadIdx.x >> 5; // 32 x 8
  #pragma unroll
  for (int i = 0; i < 32; i += 8)
    tile[ty + i][tx] = W[(size_t)(bk + ty + i) * N + bn + tx];
  __syncthreads();
  #pragma unroll
  for (int i = 0; i < 32; i += 8)
    Wt[(size_t)(bn + ty + i) * K + bk + tx] = f2bf(tile[tx][ty + i]);
}

// ---------------- Elementwise cast fp32 -> bf16 ----------------------------
__global__ __launch_bounds__(256) void cast_bf16_kernel(
    const float* __restrict__ in, u16* __restrict__ out, int n)
{
  int i = (blockIdx.x * 256 + threadIdx.x) * 4;
  if (i >= n) return;
  float4 v = *(const float4*)&in[i];
  ushort4 o;
  o.x = f2bf(v.x); o.y = f2bf(v.y); o.z = f2bf(v.z); o.w = f2bf(v.w);
  *(ushort4*)&out[i] = o;
}

// ---------------- 128xTN MFMA GEMM, BK=64, global_load_lds staging ---------
template<int TN, int MODE>
__global__ __launch_bounds__(256) void gemm_bf16(
    const u16* __restrict__ A, const u16* __restrict__ Bt,
    const float* __restrict__ bias, const float* __restrict__ res,
    float* __restrict__ outF, u16* __restrict__ outB0,
    u16* __restrict__ outB1, u16* __restrict__ outB2,
    int M, int N, int K)
{
  constexpr int NI = TN / 32;       // n-frags per wave
  __shared__ u16 sA[128 * 64];
  __shared__ u16 sB[TN * 64];
  int tid = threadIdx.x;
  int lane = tid & 63, wv = tid >> 6;
  int wm = wv >> 1, wn = wv & 1;
  int g = lane >> 4, l15 = lane & 15;
  int m0 = blockIdx.y * 128, n0 = blockIdx.x * TN;

  f32x4 acc[4][NI] = {};
  for (int k0 = 0; k0 < K; k0 += 64) {
    __syncthreads();
    #pragma unroll
    for (int s = 0; s < 4; ++s) {           // A: 128 rows x 8 chunks
      int c = s * 256 + tid;
      int row = c >> 3, p = c & 7;
      gll16(&A[(size_t)(m0 + row) * K + k0 + ((p ^ (row & 7)) * 8)],
            &sA[(size_t)(s * 256 + wv * 64) * 8]);
    }
    #pragma unroll
    for (int s = 0; s < TN / 32; ++s) {     // B: TN rows x 8 chunks
      int c = s * 256 + tid;
      int row = c >> 3, p = c & 7;
      gll16(&Bt[(size_t)(n0 + row) * K + k0 + ((p ^ (row & 7)) * 8)],
            &sB[(size_t)(s * 256 + wv * 64) * 8]);
    }
    asm volatile("s_waitcnt vmcnt(0)" ::: "memory");
    __syncthreads();
    #pragma unroll
    for (int kk = 0; kk < 2; ++kk) {
      short8 af[4], bfr[NI];
      #pragma unroll
      for (int i = 0; i < 4; ++i) {
        int row = wm * 64 + i * 16 + l15;
        af[i] = *(const short8*)&sA[row * 64 + (((4 * kk + g) ^ (row & 7)) * 8)];
      }
      #pragma unroll
      for (int i = 0; i < NI; ++i) {
        int row = wn * (TN / 2) + i * 16 + l15;
        bfr[i] = *(const short8*)&sB[row * 64 + (((4 * kk + g) ^ (row & 7)) * 8)];
      }
      #pragma unroll
      for (int mi = 0; mi < 4; ++mi)
        #pragma unroll
        for (int ni = 0; ni < NI; ++ni)
          acc[mi][ni] = __builtin_amdgcn_mfma_f32_16x16x32_bf16(af[mi], bfr[ni], acc[mi][ni], 0, 0, 0);
    }
  }

  #pragma unroll
  for (int mi = 0; mi < 4; ++mi) {
    #pragma unroll
    for (int ni = 0; ni < NI; ++ni) {
      #pragma unroll
      for (int r = 0; r < 4; ++r) {
        int grow = m0 + wm * 64 + mi * 16 + g * 4 + r;
        int gcol = n0 + wn * (TN / 2) + ni * 16 + l15;
        float val = acc[mi][ni][r] + bias[gcol];
        if (MODE == 0) {
          int part = gcol >> 9, c = gcol & 511;
          int hh = c >> 6, dd = c & 63;
          int bb = grow >> 11, ss = grow & 2047;
          size_t dst = (((size_t)(bb * NH + hh)) * SEQ + ss) * DH + dd;
          if (part == 0)      outB0[dst] = f2bf(val * 0.18033688011112042f); // q * 0.125*log2(e)
          else if (part == 1) outB1[dst] = f2bf(val);           // k
          else                outB2[dst] = f2bf(val);           // v
        } else if (MODE == 1 || MODE == 3) {
          size_t idx = (size_t)grow * DM + gcol;
          outF[idx] = val + res[idx];
        } else { // MODE 2: gelu (tanh approx = jax.nn.gelu default)
          float t = val;
          float inner = 0.7978845608028654f * (t + 0.044715f * t * t * t);
          float gl = 0.5f * t * (1.0f + tanhf(inner));
          outB0[(size_t)grow * N + gcol] = f2bf(gl);
        }
      }
    }
  }
}

// ---------------- Flash causal attention with relative positions -----------
// Balanced fold: 256 blocks; block (bh,p) serially does q-tile p then 31-p,
// exactly 17 lockstep iterations of KVB=128 columns. 4 waves x 16 q-rows.
__global__ __launch_bounds__(256, 1) void attn_kernel(
    const u16* __restrict__ Q, const u16* __restrict__ Kb,
    const u16* __restrict__ Vb, const u16* __restrict__ Eb,
    u16* __restrict__ Ob)
{
  __shared__ u16 sK[2][KVB * 64];        // 32KB, chunk-swizzled linear (gll)
  __shared__ u16 sV[2][64 * (KVB + 8)];  // 34.8KB, [d][t] block-XOR
  __shared__ u16 sP[4][16 * KVB];        // 16KB, per-wave, 4-bit XOR chunks

  int tid = threadIdx.x, lane = tid & 63, wv = tid >> 6;
  int g = lane >> 4, l15 = lane & 15;
  int blk = blockIdx.x;
  int bh = blk >> 4, p = blk & 15;
  int hh = bh & (NH - 1), bb = bh >> 3;

  const u16* Qh = Q  + (size_t)bh * SEQ * DH;
  const u16* Kh = Kb + (size_t)bh * SEQ * DH;
  const u16* Vh = Vb + (size_t)bh * SEQ * DH;
  const u16* Eh = Eb + (size_t)hh * SEQ * DH;

  int tileA = p, tileB = 31 - p;
  int itersA = p / 2 + 1;
  const int TOT = 17;

  int rstage = tid >> 3, cstage = (tid & 7) * 8;

  // ---- prologue: stage kt=0 into buffer 0 ----
  #pragma unroll
  for (int s = 0; s < 4; ++s) {
    int c = s * 256 + tid, t = c >> 3, pc = c & 7;
    gll16(&Kh[(size_t)t * DH + ((pc ^ (t & 7)) * 8)],
          &sK[0][(size_t)(s * 256 + wv * 64) * 8]);
  }
  #pragma unroll
  for (int q = 0; q < 4; ++q) {
    int t = q * 32 + rstage;
    short8 vv = *(const short8*)&Vh[(size_t)t * DH + cstage];
    #pragma unroll
    for (int j = 0; j < 8; ++j) {
      int d = cstage + j;
      sV[0][d * (KVB + 8) + (((t >> 3) ^ (d >> 3)) * 8) + (t & 7)] = (u16)vv[j];
    }
  }
  asm volatile("s_waitcnt vmcnt(0)" ::: "memory");
  __syncthreads();

  short8 qf[2];
  {
    int sw = tileA * 64 + wv * 16;
    qf[0] = *(const short8*)&Qh[(size_t)(sw + l15) * DH + g * 8];
    qf[1] = *(const short8*)&Qh[(size_t)(sw + l15) * DH + g * 8 + 32];
  }
  f32x4 o[4] = {};
  float mrow[4] = {-1e30f, -1e30f, -1e30f, -1e30f};
  float lsum[4] = {};
  f32x4 relC;
  bool haveC = false;

  auto flushOut = [&](int tile) {
    int sw = tile * 64 + wv * 16;
    #pragma unroll
    for (int nb = 0; nb < 4; ++nb)
      #pragma unroll
      for (int r = 0; r < 4; ++r) {
        int ss = sw + g * 4 + r, dd = nb * 16 + l15;
        Ob[((size_t)(bb * SEQ + ss)) * DM + hh * DH + dd] = f2bf(o[nb][r] / lsum[r]);
      }
  };

  for (int it = 0; it < TOT; ++it) {
    int cur = it & 1;
    if (it == itersA) {
      flushOut(tileA);
      #pragma unroll
      for (int nb = 0; nb < 4; ++nb) o[nb] = f32x4{};
      #pragma unroll
      for (int r = 0; r < 4; ++r) { mrow[r] = -1e30f; lsum[r] = 0.f; }
      haveC = false;
      int sw = tileB * 64 + wv * 16;
      qf[0] = *(const short8*)&Qh[(size_t)(sw + l15) * DH + g * 8];
      qf[1] = *(const short8*)&Qh[(size_t)(sw + l15) * DH + g * 8 + 32];
    }
    int tile = (it < itersA) ? tileA : tileB;
    int kt   = (it < itersA) ? it : it - itersA;
    int sw = tile * 64 + wv * 16, t0 = kt * KVB;
    int jbase = 2032 - sw + t0;

    // prefetch next tile's K (async->LDS) and V (->regs); t-base = kt only
    bool pre = (it + 1 < TOT);
    short8 vp[4];
    if (pre) {
      int kn = (it + 1 < itersA) ? it + 1 : it + 1 - itersA;
      int tb = kn * KVB;
      #pragma unroll
      for (int s = 0; s < 4; ++s) {
        int c = s * 256 + tid, t = c >> 3, pc = c & 7;
        gll16(&Kh[(size_t)(tb + t) * DH + ((pc ^ (t & 7)) * 8)],
              &sK[cur ^ 1][(size_t)(s * 256 + wv * 64) * 8]);
      }
      #pragma unroll
      for (int q = 0; q < 4; ++q)
        vp[q] = *(const short8*)&Vh[(size_t)(tb + q * 32 + rstage) * DH + cstage];
    }

    // S1 = Q K^T (16 x 128 per wave)
    f32x4 accS[8];
    #pragma unroll
    for (int ni = 0; ni < 8; ++ni) {
      int row = ni * 16 + l15;
      short8 k0 = *(const short8*)&sK[cur][row * 64 + ((g ^ (row & 7)) * 8)];
      short8 k1 = *(const short8*)&sK[cur][row * 64 + (((4 + g) ^ (row & 7)) * 8)];
      f32x4 z = {};
      z = __builtin_amdgcn_mfma_f32_16x16x32_bf16(qf[0], k0, z, 0, 0, 0);
      z = __builtin_amdgcn_mfma_f32_16x16x32_bf16(qf[1], k1, z, 0, 0, 0);
      accS[ni] = z;
    }

    // S2 = Q E^T strip (16 x 144), rel[s,t] = q[s].E[jbase + 15-srow + tcol]
    f32x4 accR[9];
    if (haveC) {
      accR[0] = relC;
    } else {
      int j = jbase + l15; if (j > 2047) j = 2047;
      short8 e0 = *(const short8*)&Eh[(size_t)j * DH + g * 8];
      short8 e1 = *(const short8*)&Eh[(size_t)j * DH + 32 + g * 8];
      f32x4 z = {};
      z = __builtin_amdgcn_mfma_f32_16x16x32_bf16(qf[0], e0, z, 0, 0, 0);
      z = __builtin_amdgcn_mfma_f32_16x16x32_bf16(qf[1], e1, z, 0, 0, 0);
      accR[0] = z;
    }
    #pragma unroll
    for (int nb = 1; nb < 9; ++nb) {
      int j = jbase + nb * 16 + l15; if (j > 2047) j = 2047;
      short8 e0 = *(const short8*)&Eh[(size_t)j * DH + g * 8];
      short8 e1 = *(const short8*)&Eh[(size_t)j * DH + 32 + g * 8];
      f32x4 z = {};
      z = __builtin_amdgcn_mfma_f32_16x16x32_bf16(qf[0], e0, z, 0, 0, 0);
      z = __builtin_amdgcn_mfma_f32_16x16x32_bf16(qf[1], e1, z, 0, 0, 0);
      accR[nb] = z;
    }
    relC = accR[8];
    haveC = (it + 1 != itersA);

    // skew realign via in-group shuffles + combine + mask
    bool needMask = (t0 + KVB - 1 > sw);
    #pragma unroll
    for (int r = 0; r < 4; ++r) {
      int srow = g * 4 + r;
      int dsh = 15 - srow + l15;                 // 0..30
      int srcl = (lane & 48) + (dsh & 15);
      float sh[9];
      #pragma unroll
      for (int nb = 0; nb < 9; ++nb) sh[nb] = __shfl(accR[nb][r], srcl);
      bool cy = dsh >= 16;
      #pragma unroll
      for (int ni = 0; ni < 8; ++ni) {
        float rel = cy ? sh[ni + 1] : sh[ni];
        float val = accS[ni][r] + rel;
        if (needMask && (t0 + ni * 16 + l15 > sw + srow)) val = -1e30f;
        accS[ni][r] = val;
      }
    }

    // online softmax (exp2; q pre-scaled by log2e/8)
    #pragma unroll
    for (int r = 0; r < 4; ++r) {
      float tm = accS[0][r];
      #pragma unroll
      for (int ni = 1; ni < 8; ++ni) tm = fmaxf(tm, accS[ni][r]);
      tm = fmaxf(tm, __shfl_xor(tm, 1));
      tm = fmaxf(tm, __shfl_xor(tm, 2));
      tm = fmaxf(tm, __shfl_xor(tm, 4));
      tm = fmaxf(tm, __shfl_xor(tm, 8));
      float mnew = fmaxf(mrow[r], tm);
      float scl = exp2f(mrow[r] - mnew);
      mrow[r] = mnew;
      float se = 0.f;
      #pragma unroll
      for (int ni = 0; ni < 8; ++ni) {
        float pe = exp2f(accS[ni][r] - mnew);
        accS[ni][r] = pe;
        se += pe;
      }
      se += __shfl_xor(se, 1); se += __shfl_xor(se, 2);
      se += __shfl_xor(se, 4); se += __shfl_xor(se, 8);
      lsum[r] = lsum[r] * scl + se;
      o[0][r] *= scl; o[1][r] *= scl; o[2][r] *= scl; o[3][r] *= scl;
    }

    // P -> per-wave LDS (4-bit XOR chunk layout), then PV
    #pragma unroll
    for (int ni = 0; ni < 8; ++ni)
      #pragma unroll
      for (int r = 0; r < 4; ++r) {
        int srow = g * 4 + r;
        int chunk = (ni * 2 + (l15 >> 3)) ^ srow;
        sP[wv][srow * KVB + chunk * 8 + (l15 & 7)] = f2bf(accS[ni][r]);
      }
    asm volatile("s_waitcnt lgkmcnt(0)" ::: "memory");
    __builtin_amdgcn_sched_barrier(0);
    #pragma unroll
    for (int kk = 0; kk < 4; ++kk) {
      short8 pf = *(const short8*)&sP[wv][l15 * KVB + (((kk * 4 + g) ^ l15) * 8)];
      #pragma unroll
      for (int nb = 0; nb < 4; ++nb) {
        int d = nb * 16 + l15;
        short8 vf = *(const short8*)&sV[cur][d * (KVB + 8) + (((kk * 4 + g) ^ (d >> 3)) * 8)];
        o[nb] = __builtin_amdgcn_mfma_f32_16x16x32_bf16(pf, vf, o[nb], 0, 0, 0);
      }
    }

    // write prefetched V^T into the other buffer; drain K gll; barrier
    if (pre) {
      #pragma unroll
      for (int q = 0; q < 4; ++q) {
        int t = q * 32 + rstage;
        #pragma unroll
        for (int j = 0; j < 8; ++j) {
          int d = cstage + j;
          sV[cur ^ 1][d * (KVB + 8) + (((t >> 3) ^ (d >> 3)) * 8) + (t & 7)] = (u16)vp[q][j];
        }
      }
    }
    asm volatile("s_waitcnt vmcnt(0)" ::: "memory");
    __syncthreads();
  }

  flushOut(tileB);
}

// ---------------------------------------------------------------------------
extern "C" void kernel_launch(void* const* d_in, const int* in_sizes, int n_in,
                              void* d_out, int out_size, void* d_ws, size_t ws_size,
                              hipStream_t stream) {
  const float* x     = (const float*)d_in[0];
  // d_in[1] = mask: recomputed causally in-kernel
  const float* Wqkv  = (const float*)d_in[2];
  const float* bqkv  = (const float*)d_in[3];
  const float* Wproj = (const float*)d_in[4];
  const float* bproj = (const float*)d_in[5];
  const float* E     = (const float*)d_in[6];
  const float* g1    = (const float*)d_in[7];
  const float* b1    = (const float*)d_in[8];
  const float* g2    = (const float*)d_in[9];
  const float* b2    = (const float*)d_in[10];
  const float* W1    = (const float*)d_in[11];
  const float* bm1   = (const float*)d_in[12];
  const float* W2    = (const float*)d_in[13];
  const float* bm2   = (const float*)d_in[14];
  float* out = (float*)d_out;

  char* ws = (char*)d_ws;
  size_t off = 0;
  auto alloc = [&](size_t bytes) {
    void* p = ws + off;
    off += (bytes + 255) & ~(size_t)255;
    return p;
  };
  u16* a_bf   = (u16*)alloc((size_t)NROWS * DM * 2);      // LN1 out, reused for LN2 out
  u16* q_bf   = (u16*)alloc((size_t)NROWS * DM * 2);
  u16* k_bf   = (u16*)alloc((size_t)NROWS * DM * 2);
  u16* v_bf   = (u16*)alloc((size_t)NROWS * DM * 2);
  u16* att_bf = (u16*)alloc((size_t)NROWS * DM * 2);
  float* y    = (float*)alloc((size_t)NROWS * DM * 4);
  u16* h_bf   = (u16*)alloc((size_t)NROWS * 2048 * 2);
  u16* WqkvT  = (u16*)alloc((size_t)1536 * 512 * 2);
  u16* WprojT = (u16*)alloc((size_t)512 * 512 * 2);
  u16* W1T    = (u16*)alloc((size_t)2048 * 512 * 2);
  u16* W2T    = (u16*)alloc((size_t)512 * 2048 * 2);
  u16* E_bf   = (u16*)alloc((size_t)NH * SEQ * DH * 2);

  // weights -> bf16 (transposed to N x K)
  transpose_cast_kernel<<<dim3(1536 / 32, 512 / 32), 256, 0, stream>>>(Wqkv, WqkvT, 512, 1536);
  transpose_cast_kernel<<<dim3(512 / 32, 512 / 32), 256, 0, stream>>>(Wproj, WprojT, 512, 512);
  transpose_cast_kernel<<<dim3(2048 / 32, 512 / 32), 256, 0, stream>>>(W1, W1T, 512, 2048);
  transpose_cast_kernel<<<dim3(512 / 32, 2048 / 32), 256, 0, stream>>>(W2, W2T, 2048, 512);
  cast_bf16_kernel<<<(NH * SEQ * DH) / (256 * 4), 256, 0, stream>>>(E, E_bf, NH * SEQ * DH);

  // LN1
  ln_bf16_kernel<<<NROWS, 64, 0, stream>>>(x, g1, b1, a_bf);
  // QKV (q pre-scaled by 0.125*log2e for exp2-softmax)
  gemm_bf16<128, 0><<<dim3(1536 / 128, NROWS / 128), 256, 0, stream>>>(
      a_bf, WqkvT, bqkv, nullptr, nullptr, q_bf, k_bf, v_bf, NROWS, 1536, 512);
  // attention (balanced fold schedule)
  attn_kernel<<<256, 256, 0, stream>>>(q_bf, k_bf, v_bf, E_bf, att_bf);
  // proj + residual -> y (fp32)
  gemm_bf16<64, 1><<<dim3(512 / 64, NROWS / 128), 256, 0, stream>>>(
      att_bf, WprojT, bproj, x, y, nullptr, nullptr, nullptr, NROWS, 512, 512);
  // LN2 (reuse a_bf as m_bf)
  ln_bf16_kernel<<<NROWS, 64, 0, stream>>>(y, g2, b2, a_bf);
  // FFN1 + gelu
  gemm_bf16<128, 2><<<dim3(2048 / 128, NROWS / 128), 256, 0, stream>>>(
      a_bf, W1T, bm1, nullptr, nullptr, h_bf, nullptr, nullptr, NROWS, 2048, 512);
  // FFN2 + residual -> out
  gemm_bf16<64, 3><<<dim3(512 / 64, NROWS / 128), 256, 0, stream>>>(
      h_bf, W2T, bm2, y, out, nullptr, nullptr, nullptr, NROWS, 512, 2048);
}

// Round 4
// 189.794 us; speedup vs baseline: 1.3884x; 1.1002x over previous
//
#include <hip/hip_runtime.h>
#include <math.h>

typedef unsigned short u16;
typedef unsigned int u32;
using short8 = __attribute__((ext_vector_type(8))) short;
using f32x4  = __attribute__((ext_vector_type(4))) float;

#define SEQ 2048
#define NH 8
#define DM 512
#define DH 64
#define NROWS 4096  // B*S
#define BATCH 2
#define KVB 128

__device__ __forceinline__ float bf2f(u16 u) {
  union { u32 i; float f; } c; c.i = ((u32)u) << 16; return c.f;
}
__device__ __forceinline__ u16 f2bf(float f) {
  union { float f; u32 i; } c; c.f = f;
  u32 r = c.i + 0x7fffu + ((c.i >> 16) & 1u);
  return (u16)(r >> 16);
}

// async global->LDS, 16B per lane. LDS dest must be wave-uniform base.
__device__ __forceinline__ void gll16(const u16* g, u16* l) {
  __builtin_amdgcn_global_load_lds(
      (const __attribute__((address_space(1))) u32*)g,
      (__attribute__((address_space(3))) u32*)l, 16, 0, 0);
}

// ---------------- LayerNorm (fp32 in -> bf16 out), one wave per 512-row ----
__global__ __launch_bounds__(64) void ln_bf16_kernel(
    const float* __restrict__ x, const float* __restrict__ gw,
    const float* __restrict__ bw, u16* __restrict__ out)
{
  int row = blockIdx.x;
  int lane = threadIdx.x;
  const float* xr = x + (size_t)row * DM;
  float4 v0 = ((const float4*)xr)[lane];
  float4 v1 = ((const float4*)xr)[lane + 64];
  float s  = v0.x + v0.y + v0.z + v0.w + v1.x + v1.y + v1.z + v1.w;
  float s2 = v0.x*v0.x + v0.y*v0.y + v0.z*v0.z + v0.w*v0.w
           + v1.x*v1.x + v1.y*v1.y + v1.z*v1.z + v1.w*v1.w;
  #pragma unroll
  for (int m = 1; m < 64; m <<= 1) {
    s  += __shfl_xor(s,  m);
    s2 += __shfl_xor(s2, m);
  }
  float mu   = s * (1.0f / DM);
  float var  = s2 * (1.0f / DM) - mu * mu;
  float rstd = rsqrtf(var + 1e-5f);
  float4 ga = ((const float4*)gw)[lane],      ba = ((const float4*)bw)[lane];
  float4 gb = ((const float4*)gw)[lane + 64], bb = ((const float4*)bw)[lane + 64];
  ushort4 o0, o1;
  o0.x = f2bf((v0.x - mu) * rstd * ga.x + ba.x);
  o0.y = f2bf((v0.y - mu) * rstd * ga.y + ba.y);
  o0.z = f2bf((v0.z - mu) * rstd * ga.z + ba.z);
  o0.w = f2bf((v0.w - mu) * rstd * ga.w + ba.w);
  o1.x = f2bf((v1.x - mu) * rstd * gb.x + bb.x);
  o1.y = f2bf((v1.y - mu) * rstd * gb.y + bb.y);
  o1.z = f2bf((v1.z - mu) * rstd * gb.z + bb.z);
  o1.w = f2bf((v1.w - mu) * rstd * gb.w + bb.w);
  *(ushort4*)&out[(size_t)row * DM + lane * 4]       = o0;
  *(ushort4*)&out[(size_t)row * DM + 256 + lane * 4] = o1;
}

// ---------------- Transpose + cast fp32 (K x N) -> bf16 (N x K) ------------
__global__ __launch_bounds__(256) void transpose_cast_kernel(
    const float* __restrict__ W, u16* __restrict__ Wt, int K, int N)
{
  __shared__ float tile[32][33];
  int bn = blockIdx.x * 32, bk = blockIdx.y * 32;
  int tx = threadIdx.x & 31, ty = threadIdx.x >> 5; // 32 x 8
  #pragma unroll
  for (int i = 0; i < 32; i += 8)
    tile[ty + i][tx] = W[(size_t)(bk + ty + i) * N + bn + tx];
  __syncthreads();
  #pragma unroll
  for (int i = 0; i < 32; i += 8)
    Wt[(size_t)(bn + ty + i) * K + bk + tx] = f2bf(tile[tx][ty + i]);
}

// ---------------- Elementwise cast fp32 -> bf16 ----------------------------
__global__ __launch_bounds__(256) void cast_bf16_kernel(
    const float* __restrict__ in, u16* __restrict__ out, int n)
{
  int i = (blockIdx.x * 256 + threadIdx.x) * 4;
  if (i >= n) return;
  float4 v = *(const float4*)&in[i];
  ushort4 o;
  o.x = f2bf(v.x); o.y = f2bf(v.y); o.z = f2bf(v.z); o.w = f2bf(v.w);
  *(ushort4*)&out[i] = o;
}

// ---------------- 128xTN MFMA GEMM, BK=64, global_load_lds staging ---------
template<int TN, int MODE>
__global__ __launch_bounds__(256) void gemm_bf16(
    const u16* __restrict__ A, const u16* __restrict__ Bt,
    const float* __restrict__ bias, const float* __restrict__ res,
    float* __restrict__ outF, u16* __restrict__ outB0,
    u16* __restrict__ outB1, u16* __restrict__ outB2,
    int M, int N, int K)
{
  constexpr int NI = TN / 32;       // n-frags per wave
  __shared__ u16 sA[128 * 64];
  __shared__ u16 sB[TN * 64];
  int tid = threadIdx.x;
  int lane = tid & 63, wv = tid >> 6;
  int wm = wv >> 1, wn = wv & 1;
  int g = lane >> 4, l15 = lane & 15;
  int m0 = blockIdx.y * 128, n0 = blockIdx.x * TN;

  f32x4 acc[4][NI] = {};
  for (int k0 = 0; k0 < K; k0 += 64) {
    __syncthreads();
    #pragma unroll
    for (int s = 0; s < 4; ++s) {           // A: 128 rows x 8 chunks
      int c = s * 256 + tid;
      int row = c >> 3, p = c & 7;
      gll16(&A[(size_t)(m0 + row) * K + k0 + ((p ^ (row & 7)) * 8)],
            &sA[(size_t)(s * 256 + wv * 64) * 8]);
    }
    #pragma unroll
    for (int s = 0; s < TN / 32; ++s) {     // B: TN rows x 8 chunks
      int c = s * 256 + tid;
      int row = c >> 3, p = c & 7;
      gll16(&Bt[(size_t)(n0 + row) * K + k0 + ((p ^ (row & 7)) * 8)],
            &sB[(size_t)(s * 256 + wv * 64) * 8]);
    }
    asm volatile("s_waitcnt vmcnt(0)" ::: "memory");
    __syncthreads();
    #pragma unroll
    for (int kk = 0; kk < 2; ++kk) {
      short8 af[4], bfr[NI];
      #pragma unroll
      for (int i = 0; i < 4; ++i) {
        int row = wm * 64 + i * 16 + l15;
        af[i] = *(const short8*)&sA[row * 64 + (((4 * kk + g) ^ (row & 7)) * 8)];
      }
      #pragma unroll
      for (int i = 0; i < NI; ++i) {
        int row = wn * (TN / 2) + i * 16 + l15;
        bfr[i] = *(const short8*)&sB[row * 64 + (((4 * kk + g) ^ (row & 7)) * 8)];
      }
      #pragma unroll
      for (int mi = 0; mi < 4; ++mi)
        #pragma unroll
        for (int ni = 0; ni < NI; ++ni)
          acc[mi][ni] = __builtin_amdgcn_mfma_f32_16x16x32_bf16(af[mi], bfr[ni], acc[mi][ni], 0, 0, 0);
    }
  }

  #pragma unroll
  for (int mi = 0; mi < 4; ++mi) {
    #pragma unroll
    for (int ni = 0; ni < NI; ++ni) {
      #pragma unroll
      for (int r = 0; r < 4; ++r) {
        int grow = m0 + wm * 64 + mi * 16 + g * 4 + r;
        int gcol = n0 + wn * (TN / 2) + ni * 16 + l15;
        float val = acc[mi][ni][r] + bias[gcol];
        if (MODE == 0) {
          int part = gcol >> 9, c = gcol & 511;
          int hh = c >> 6, dd = c & 63;
          int bb = grow >> 11, ss = grow & 2047;
          size_t dst = (((size_t)(bb * NH + hh)) * SEQ + ss) * DH + dd;
          if (part == 0)      outB0[dst] = f2bf(val * 0.18033688011112042f); // q * 0.125*log2(e)
          else if (part == 1) outB1[dst] = f2bf(val);           // k
          else                outB2[dst] = f2bf(val);           // v
        } else if (MODE == 1 || MODE == 3) {
          size_t idx = (size_t)grow * DM + gcol;
          outF[idx] = val + res[idx];
        } else { // MODE 2: gelu (tanh approx = jax.nn.gelu default)
          float t = val;
          float inner = 0.7978845608028654f * (t + 0.044715f * t * t * t);
          float gl = 0.5f * t * (1.0f + tanhf(inner));
          outB0[(size_t)grow * N + gcol] = f2bf(gl);
        }
      }
    }
  }
}

// ---------------- Flash causal attention with relative positions -----------
// 512 blocks (2/CU): block = (bh, pp) handles fold pair of 32-row q-tiles
// (pp, 63-pp): always exactly 17 iterations of KVB=128. 4 waves =
// 2 row-groups x 2 column-halves; online softmax shared across column
// halves via LDS; O-halves combined at flush.
__global__ __launch_bounds__(256, 2) void attn_kernel(
    const u16* __restrict__ Q, const u16* __restrict__ Kb,
    const u16* __restrict__ Vb, const u16* __restrict__ Eb,
    u16* __restrict__ Ob)
{
  __shared__ u16 sK[2][KVB * 64];        // 32KB, chunk-swizzled linear (gll)
  __shared__ u16 sV[64 * (KVB + 8)];     // 17.4KB, [d][t] block-XOR, single
  __shared__ u16 sP[4][16 * 64];         // 8KB, per-wave (sO overlays)
  __shared__ float sM[2][32];            // cross-half max exchange
  __shared__ float sS[2][32];            // cross-half sum exchange

  int tid = threadIdx.x, lane = tid & 63, wv = tid >> 6;
  int wr = wv & 1, wc = wv >> 1;
  int g = lane >> 4, l15 = lane & 15;
  int blk = blockIdx.x;
  int bh = blk >> 5, pp = blk & 31;
  int hh = bh & (NH - 1), bb = bh >> 3;

  const u16* Qh = Q  + (size_t)bh * SEQ * DH;
  const u16* Kh = Kb + (size_t)bh * SEQ * DH;
  const u16* Vh = Vb + (size_t)bh * SEQ * DH;
  const u16* Eh = Eb + (size_t)hh * SEQ * DH;

  int tileA = pp, tileB = 63 - pp;
  int itersA = pp / 4 + 1;
  const int TOT = 17;

  int rstage = tid >> 3, cstage = (tid & 7) * 8;

  // ---- prologue: stage kt=0 ----
  #pragma unroll
  for (int s = 0; s < 4; ++s) {
    int c = s * 256 + tid, t = c >> 3, pc = c & 7;
    gll16(&Kh[(size_t)t * DH + ((pc ^ (t & 7)) * 8)],
          &sK[0][(size_t)(s * 256 + wv * 64) * 8]);
  }
  #pragma unroll
  for (int q = 0; q < 4; ++q) {
    int t = q * 32 + rstage;
    short8 vv = *(const short8*)&Vh[(size_t)t * DH + cstage];
    #pragma unroll
    for (int j = 0; j < 8; ++j) {
      int d = cstage + j;
      sV[d * (KVB + 8) + (((t >> 3) ^ (d >> 3)) * 8) + (t & 7)] = (u16)vv[j];
    }
  }
  asm volatile("s_waitcnt vmcnt(0)" ::: "memory");
  __syncthreads();

  short8 qf[2];
  {
    int sw = tileA * 32 + wr * 16;
    qf[0] = *(const short8*)&Qh[(size_t)(sw + l15) * DH + g * 8];
    qf[1] = *(const short8*)&Qh[(size_t)(sw + l15) * DH + g * 8 + 32];
  }
  f32x4 o[4] = {};
  float mrow[4] = {-1e30f, -1e30f, -1e30f, -1e30f};
  float lsum[4] = {};

  float* sO = (float*)&sP[0][0];   // [2][16][64] f32 overlay at flush time

  auto flushOut = [&](int tile) {
    int swt = tile * 32 + wr * 16;
    if (wc == 1) {
      #pragma unroll
      for (int r = 0; r < 4; ++r) {
        float rl = 1.0f / lsum[r];
        #pragma unroll
        for (int nb = 0; nb < 4; ++nb)
          sO[wr * 1024 + (g * 4 + r) * 64 + nb * 16 + l15] = o[nb][r] * rl;
      }
    }
    __syncthreads();
    if (wc == 0) {
      #pragma unroll
      for (int r = 0; r < 4; ++r) {
        float rl = 1.0f / lsum[r];
        int ss = swt + g * 4 + r;
        #pragma unroll
        for (int nb = 0; nb < 4; ++nb) {
          float val = o[nb][r] * rl + sO[wr * 1024 + (g * 4 + r) * 64 + nb * 16 + l15];
          Ob[((size_t)(bb * SEQ + ss)) * DM + hh * DH + nb * 16 + l15] = f2bf(val);
        }
      }
    }
  };

  for (int it = 0; it < TOT; ++it) {
    int cur = it & 1;
    if (it == itersA) {
      flushOut(tileA);
      #pragma unroll
      for (int nb = 0; nb < 4; ++nb) o[nb] = f32x4{};
      #pragma unroll
      for (int r = 0; r < 4; ++r) { mrow[r] = -1e30f; lsum[r] = 0.f; }
      int sw = tileB * 32 + wr * 16;
      qf[0] = *(const short8*)&Qh[(size_t)(sw + l15) * DH + g * 8];
      qf[1] = *(const short8*)&Qh[(size_t)(sw + l15) * DH + g * 8 + 32];
    }
    int tile = (it < itersA) ? tileA : tileB;
    int kt   = (it < itersA) ? it : it - itersA;
    int sw = tile * 32 + wr * 16, t0 = kt * KVB;

    // prefetch next K (async->LDS) and V (->regs)
    bool pre = (it + 1 < TOT);
    short8 vp[4];
    if (pre) {
      int kn = (it + 1 < itersA) ? it + 1 : it + 1 - itersA;
      int tb = kn * KVB;
      #pragma unroll
      for (int s = 0; s < 4; ++s) {
        int c = s * 256 + tid, t = c >> 3, pc = c & 7;
        gll16(&Kh[(size_t)(tb + t) * DH + ((pc ^ (t & 7)) * 8)],
              &sK[cur ^ 1][(size_t)(s * 256 + wv * 64) * 8]);
      }
      #pragma unroll
      for (int q = 0; q < 4; ++q)
        vp[q] = *(const short8*)&Vh[(size_t)(tb + q * 32 + rstage) * DH + cstage];
    }

    // S1 = Q K^T (16 rows x 64 cols per wave, this wave's column half)
    f32x4 accS[4];
    #pragma unroll
    for (int ni = 0; ni < 4; ++ni) {
      int row = wc * 64 + ni * 16 + l15;
      short8 k0 = *(const short8*)&sK[cur][row * 64 + ((g ^ (row & 7)) * 8)];
      short8 k1 = *(const short8*)&sK[cur][row * 64 + (((4 + g) ^ (row & 7)) * 8)];
      f32x4 z = {};
      z = __builtin_amdgcn_mfma_f32_16x16x32_bf16(qf[0], k0, z, 0, 0, 0);
      z = __builtin_amdgcn_mfma_f32_16x16x32_bf16(qf[1], k1, z, 0, 0, 0);
      accS[ni] = z;
    }

    // S2 = Q E^T strip (16 x 80): rel[s,t] = q[s].E[2047 - s + t]
    int jbase = 2032 - sw + t0 + wc * 64;
    f32x4 accR[5];
    #pragma unroll
    for (int nb = 0; nb < 5; ++nb) {
      int j = jbase + nb * 16 + l15; if (j > 2047) j = 2047;
      short8 e0 = *(const short8*)&Eh[(size_t)j * DH + g * 8];
      short8 e1 = *(const short8*)&Eh[(size_t)j * DH + 32 + g * 8];
      f32x4 z = {};
      z = __builtin_amdgcn_mfma_f32_16x16x32_bf16(qf[0], e0, z, 0, 0, 0);
      z = __builtin_amdgcn_mfma_f32_16x16x32_bf16(qf[1], e1, z, 0, 0, 0);
      accR[nb] = z;
    }

    // skew realign + combine + causal mask
    bool needMask = (t0 + wc * 64 + 63 > sw);
    #pragma unroll
    for (int r = 0; r < 4; ++r) {
      int srow = g * 4 + r;
      int dsh = 15 - srow + l15;                 // 0..30
      int srcl = (lane & 48) + (dsh & 15);
      float sh[5];
      #pragma unroll
      for (int nb = 0; nb < 5; ++nb) sh[nb] = __shfl(accR[nb][r], srcl);
      bool cy = dsh >= 16;
      #pragma unroll
      for (int ni = 0; ni < 4; ++ni) {
        float rel = cy ? sh[ni + 1] : sh[ni];
        float val = accS[ni][r] + rel;
        if (needMask && (t0 + wc * 64 + ni * 16 + l15 > sw + srow)) val = -1e30f;
        accS[ni][r] = val;
      }
    }

    // local row max -> exchange across column halves
    float lmax[4];
    #pragma unroll
    for (int r = 0; r < 4; ++r) {
      float tm = fmaxf(fmaxf(accS[0][r], accS[1][r]), fmaxf(accS[2][r], accS[3][r]));
      tm = fmaxf(tm, __shfl_xor(tm, 1));
      tm = fmaxf(tm, __shfl_xor(tm, 2));
      tm = fmaxf(tm, __shfl_xor(tm, 4));
      tm = fmaxf(tm, __shfl_xor(tm, 8));
      lmax[r] = tm;
    }
    if (l15 == 0) {
      #pragma unroll
      for (int r = 0; r < 4; ++r) sM[wc][wr * 16 + g * 4 + r] = lmax[r];
    }
    __syncthreads();                              // B1
    float4 om = *(float4*)&sM[wc ^ 1][wr * 16 + g * 4];

    // global max -> rescale o, exp, local sums
    float sesav[4], lscl[4];
    #pragma unroll
    for (int r = 0; r < 4; ++r) {
      float gm = fmaxf(lmax[r], ((float*)&om)[r]);
      float mnew = fmaxf(mrow[r], gm);
      lscl[r] = exp2f(mrow[r] - mnew);
      mrow[r] = mnew;
      float se = 0.f;
      #pragma unroll
      for (int ni = 0; ni < 4; ++ni) {
        float pe = exp2f(accS[ni][r] - mnew);
        accS[ni][r] = pe;
        se += pe;
      }
      se += __shfl_xor(se, 1); se += __shfl_xor(se, 2);
      se += __shfl_xor(se, 4); se += __shfl_xor(se, 8);
      sesav[r] = se;
      o[0][r] *= lscl[r]; o[1][r] *= lscl[r]; o[2][r] *= lscl[r]; o[3][r] *= lscl[r];
    }
    if (l15 == 0) {
      #pragma unroll
      for (int r = 0; r < 4; ++r) sS[wc][wr * 16 + g * 4 + r] = sesav[r];
    }

    // P -> per-wave LDS, then PV (accumulates into rescaled o)
    #pragma unroll
    for (int ni = 0; ni < 4; ++ni)
      #pragma unroll
      for (int r = 0; r < 4; ++r) {
        int srow = g * 4 + r;
        int chunk = (ni * 2 + (l15 >> 3)) ^ (srow & 7);
        sP[wv][srow * 64 + chunk * 8 + (l15 & 7)] = f2bf(accS[ni][r]);
      }
    asm volatile("s_waitcnt lgkmcnt(0)" ::: "memory");
    __builtin_amdgcn_sched_barrier(0);
    #pragma unroll
    for (int kk = 0; kk < 2; ++kk) {
      short8 pf = *(const short8*)&sP[wv][l15 * 64 + (((kk * 4 + g) ^ (l15 & 7)) * 8)];
      #pragma unroll
      for (int nb = 0; nb < 4; ++nb) {
        int d = nb * 16 + l15;
        int ck = wc * 8 + kk * 4 + g;
        short8 vf = *(const short8*)&sV[d * (KVB + 8) + ((ck ^ (d >> 3)) * 8)];
        o[nb] = __builtin_amdgcn_mfma_f32_16x16x32_bf16(pf, vf, o[nb], 0, 0, 0);
      }
    }

    __syncthreads();                              // B2 (drains vm+lgkm)
    float4 os = *(float4*)&sS[wc ^ 1][wr * 16 + g * 4];
    #pragma unroll
    for (int r = 0; r < 4; ++r)
      lsum[r] = lsum[r] * lscl[r] + sesav[r] + ((float*)&os)[r];

    // write prefetched V^T into sV (reads of this iter are done; next
    // iteration's B1 orders these writes before its PV reads)
    if (pre) {
      #pragma unroll
      for (int q = 0; q < 4; ++q) {
        int t = q * 32 + rstage;
        #pragma unroll
        for (int j = 0; j < 8; ++j) {
          int d = cstage + j;
          sV[d * (KVB + 8) + (((t >> 3) ^ (d >> 3)) * 8) + (t & 7)] = (u16)vp[q][j];
        }
      }
    }
  }

  flushOut(tileB);
}

// ---------------------------------------------------------------------------
extern "C" void kernel_launch(void* const* d_in, const int* in_sizes, int n_in,
                              void* d_out, int out_size, void* d_ws, size_t ws_size,
                              hipStream_t stream) {
  const float* x     = (const float*)d_in[0];
  // d_in[1] = mask: recomputed causally in-kernel
  const float* Wqkv  = (const float*)d_in[2];
  const float* bqkv  = (const float*)d_in[3];
  const float* Wproj = (const float*)d_in[4];
  const float* bproj = (const float*)d_in[5];
  const float* E     = (const float*)d_in[6];
  const float* g1    = (const float*)d_in[7];
  const float* b1    = (const float*)d_in[8];
  const float* g2    = (const float*)d_in[9];
  const float* b2    = (const float*)d_in[10];
  const float* W1    = (const float*)d_in[11];
  const float* bm1   = (const float*)d_in[12];
  const float* W2    = (const float*)d_in[13];
  const float* bm2   = (const float*)d_in[14];
  float* out = (float*)d_out;

  char* ws = (char*)d_ws;
  size_t off = 0;
  auto alloc = [&](size_t bytes) {
    void* p = ws + off;
    off += (bytes + 255) & ~(size_t)255;
    return p;
  };
  u16* a_bf   = (u16*)alloc((size_t)NROWS * DM * 2);      // LN1 out, reused for LN2 out
  u16* q_bf   = (u16*)alloc((size_t)NROWS * DM * 2);
  u16* k_bf   = (u16*)alloc((size_t)NROWS * DM * 2);
  u16* v_bf   = (u16*)alloc((size_t)NROWS * DM * 2);
  u16* att_bf = (u16*)alloc((size_t)NROWS * DM * 2);
  float* y    = (float*)alloc((size_t)NROWS * DM * 4);
  u16* h_bf   = (u16*)alloc((size_t)NROWS * 2048 * 2);
  u16* WqkvT  = (u16*)alloc((size_t)1536 * 512 * 2);
  u16* WprojT = (u16*)alloc((size_t)512 * 512 * 2);
  u16* W1T    = (u16*)alloc((size_t)2048 * 512 * 2);
  u16* W2T    = (u16*)alloc((size_t)512 * 2048 * 2);
  u16* E_bf   = (u16*)alloc((size_t)NH * SEQ * DH * 2);

  // weights -> bf16 (transposed to N x K)
  transpose_cast_kernel<<<dim3(1536 / 32, 512 / 32), 256, 0, stream>>>(Wqkv, WqkvT, 512, 1536);
  transpose_cast_kernel<<<dim3(512 / 32, 512 / 32), 256, 0, stream>>>(Wproj, WprojT, 512, 512);
  transpose_cast_kernel<<<dim3(2048 / 32, 512 / 32), 256, 0, stream>>>(W1, W1T, 512, 2048);
  transpose_cast_kernel<<<dim3(512 / 32, 2048 / 32), 256, 0, stream>>>(W2, W2T, 2048, 512);
  cast_bf16_kernel<<<(NH * SEQ * DH) / (256 * 4), 256, 0, stream>>>(E, E_bf, NH * SEQ * DH);

  // LN1
  ln_bf16_kernel<<<NROWS, 64, 0, stream>>>(x, g1, b1, a_bf);
  // QKV (q pre-scaled by 0.125*log2e for exp2-softmax)
  gemm_bf16<128, 0><<<dim3(1536 / 128, NROWS / 128), 256, 0, stream>>>(
      a_bf, WqkvT, bqkv, nullptr, nullptr, q_bf, k_bf, v_bf, NROWS, 1536, 512);
  // attention (balanced fold, 512 blocks, 2 blocks/CU)
  attn_kernel<<<512, 256, 0, stream>>>(q_bf, k_bf, v_bf, E_bf, att_bf);
  // proj + residual -> y (fp32)
  gemm_bf16<64, 1><<<dim3(512 / 64, NROWS / 128), 256, 0, stream>>>(
      att_bf, WprojT, bproj, x, y, nullptr, nullptr, nullptr, NROWS, 512, 512);
  // LN2 (reuse a_bf as m_bf)
  ln_bf16_kernel<<<NROWS, 64, 0, stream>>>(y, g2, b2, a_bf);
  // FFN1 + gelu
  gemm_bf16<128, 2><<<dim3(2048 / 128, NROWS / 128), 256, 0, stream>>>(
      a_bf, W1T, bm1, nullptr, nullptr, h_bf, nullptr, nullptr, NROWS, 2048, 512);
  // FFN2 + residual -> out
  gemm_bf16<64, 3><<<dim3(512 / 64, NROWS / 128), 256, 0, stream>>>(
      h_bf, W2T, bm2, y, out, nullptr, nullptr, nullptr, NROWS, 512, 2048);
}